// Round 1
// baseline (578.976 us; speedup 1.0000x reference)
//
#include <hip/hip_runtime.h>
#include <math.h>

#define HSd 64
#define WSd 64
#define Hh 512
#define Wh 512
#define Bn 4
#define C_ORIc 90
#define C_MNTc 180
#define C_OFFc 8
#define Kc 1024

// output offsets (in floats), concatenated in return order:
// minut [B,K,4], keep [B,K], enh_vis [B,H,W], mask_up*255 [B,H,W], ori_field [B,H,W]
#define O_MINUT 0
#define O_KEEP  (Bn*Kc*4)            // 16384
#define O_VIS   (O_KEEP + Bn*Kc)     // 20480
#define O_MASK  (O_VIS + Bn*Hh*Wh)   // 1069056
#define O_ORI   (O_MASK + Bn*Hh*Wh)  // 2117632

#define PI_180 0.017453292519943295f
#define TWO_PI 6.283185307179586f
#define ANG_T  0.5235987755982988f

// ---------------- small mask: 5x5 opening of round(seg) on [B,64,64] -------
__global__ __launch_bounds__(256) void small_mask_kernel(const float* __restrict__ seg,
                                                         float* __restrict__ mask_out)
{
    __shared__ float a[64][65];
    __shared__ float t[64][65];
    int b = blockIdx.x;
    const float* s = seg + b * 4096;
    for (int i = threadIdx.x; i < 4096; i += 256)
        a[i >> 6][i & 63] = rintf(s[i]);
    __syncthreads();
    // vertical min a->t  (window r-2..r+2 clipped: geodesic border)
    for (int i = threadIdx.x; i < 4096; i += 256) {
        int r = i >> 6, c = i & 63;
        int lo = max(r - 2, 0), hi = min(r + 2, 63);
        float m = 1e30f;
        for (int rr = lo; rr <= hi; rr++) m = fminf(m, a[rr][c]);
        t[r][c] = m;
    }
    __syncthreads();
    // horizontal min t->a
    for (int i = threadIdx.x; i < 4096; i += 256) {
        int r = i >> 6, c = i & 63;
        int lo = max(c - 2, 0), hi = min(c + 2, 63);
        float m = 1e30f;
        for (int cc = lo; cc <= hi; cc++) m = fminf(m, t[r][cc]);
        a[r][c] = m;
    }
    __syncthreads();
    // vertical max a->t
    for (int i = threadIdx.x; i < 4096; i += 256) {
        int r = i >> 6, c = i & 63;
        int lo = max(r - 2, 0), hi = min(r + 2, 63);
        float m = -1e30f;
        for (int rr = lo; rr <= hi; rr++) m = fmaxf(m, a[rr][c]);
        t[r][c] = m;
    }
    __syncthreads();
    // horizontal max t->global
    for (int i = threadIdx.x; i < 4096; i += 256) {
        int r = i >> 6, c = i & 63;
        int lo = max(c - 2, 0), hi = min(c + 2, 63);
        float m = -1e30f;
        for (int cc = lo; cc <= hi; cc++) m = fmaxf(m, t[r][cc]);
        mask_out[b * 4096 + i] = m;
    }
}

// ---------------- 512x512 windowed passes (k=40: lo=-19, hi=+20) -----------
template <bool ISMIN, bool BIN>
__global__ __launch_bounds__(256) void pass_v(const float* __restrict__ in,
                                              float* __restrict__ out)
{
    int c = blockIdx.x * 64 + threadIdx.x;
    int r = blockIdx.y * 4 + threadIdx.y;
    int b = blockIdx.z;
    const float* p = in + (size_t)b * Hh * Wh;
    int lo = max(r - 19, 0), hi = min(r + 20, Hh - 1);
    float acc = ISMIN ? 1e30f : -1e30f;
    for (int rr = lo; rr <= hi; rr++) {
        float v = p[rr * Wh + c];
        if (BIN) v = rintf(v);
        acc = ISMIN ? fminf(acc, v) : fmaxf(acc, v);
    }
    out[(size_t)b * Hh * Wh + (size_t)r * Wh + c] = acc;
}

template <bool ISMIN>
__global__ __launch_bounds__(256) void pass_h(const float* __restrict__ in,
                                              float* __restrict__ out)
{
    int c = blockIdx.x * 64 + threadIdx.x;
    int r = blockIdx.y * 4 + threadIdx.y;
    int b = blockIdx.z;
    const float* p = in + (size_t)b * Hh * Wh + (size_t)r * Wh;
    int lo = max(c - 19, 0), hi = min(c + 20, Wh - 1);
    float acc = ISMIN ? 1e30f : -1e30f;
    for (int cc = lo; cc <= hi; cc++)
        acc = ISMIN ? fminf(acc, p[cc]) : fmaxf(acc, p[cc]);
    out[(size_t)b * Hh * Wh + (size_t)r * Wh + c] = acc;
}

// ------- final horizontal max + mask_up*255 + ori_field + enh partials -----
__global__ __launch_bounds__(512) void final_up_kernel(const float* __restrict__ vmx,
                                                       const float* __restrict__ ori,
                                                       const float* __restrict__ enh,
                                                       float* __restrict__ out,
                                                       float* __restrict__ partials)
{
    int r = blockIdx.x, b = blockIdx.y, c = threadIdx.x;
    __shared__ float row[512];
    __shared__ float rmn[512];
    __shared__ float rmx[512];
    size_t base = (size_t)b * Hh * Wh + (size_t)r * Wh;
    row[c] = vmx[base + c];
    __syncthreads();
    int lo = max(c - 19, 0), hi = min(c + 20, Wh - 1);
    float m = -1e30f;
    for (int cc = lo; cc <= hi; cc++) m = fmaxf(m, row[cc]);
    out[O_MASK + base + c] = m * 255.0f;

    float of = 0.0f;
    if (m != 0.0f) {  // mask_up is 0/1; skip the 90-channel read when masked out
        const float* op = ori + (size_t)b * C_ORIc * Hh * Wh + (size_t)r * Wh + c;
        float best = op[0];
        int bi = 0;
        for (int ch = 1; ch < C_ORIc; ch++) {
            float v = op[(size_t)ch * Hh * Wh];
            if (v > best) { best = v; bi = ch; }
        }
        of = ((float)bi * 2.0f - 90.0f) * PI_180 * m;
    }
    out[O_ORI + base + c] = of;

    float e = enh[base + c] * m;
    rmn[c] = e; rmx[c] = e;
    __syncthreads();
    for (int s2 = 256; s2 > 0; s2 >>= 1) {
        if (c < s2) {
            rmn[c] = fminf(rmn[c], rmn[c + s2]);
            rmx[c] = fmaxf(rmx[c], rmx[c + s2]);
        }
        __syncthreads();
    }
    if (c == 0) {
        partials[(b * Hh + r) * 2 + 0] = rmn[0];
        partials[(b * Hh + r) * 2 + 1] = rmx[0];
    }
}

__global__ __launch_bounds__(512) void reduce_mm_kernel(const float* __restrict__ partials,
                                                        float* __restrict__ mm)
{
    int b = blockIdx.x, t = threadIdx.x;
    __shared__ float mn[512];
    __shared__ float mx[512];
    mn[t] = partials[(b * 512 + t) * 2 + 0];
    mx[t] = partials[(b * 512 + t) * 2 + 1];
    __syncthreads();
    for (int s = 256; s > 0; s >>= 1) {
        if (t < s) {
            mn[t] = fminf(mn[t], mn[t + s]);
            mx[t] = fmaxf(mx[t], mx[t + s]);
        }
        __syncthreads();
    }
    if (t == 0) { mm[b * 2] = mn[0]; mm[b * 2 + 1] = mx[0]; }
}

__global__ __launch_bounds__(256) void vis_kernel(const float* __restrict__ enh,
                                                  const float* __restrict__ maskout,
                                                  const float* __restrict__ mm,
                                                  float* __restrict__ vis)
{
    int idx = blockIdx.x * 256 + threadIdx.x;  // Bn*Hh*Wh total
    int b = idx >> 18;                          // 512*512 = 2^18
    float m = (maskout[idx] != 0.0f) ? 1.0f : 0.0f;
    float e = enh[idx] * m;
    float emin = mm[b * 2], emax = mm[b * 2 + 1];
    float r = (e - emin) / (emax - emin + 1e-8f);
    vis[idx] = r * 255.0f;
}

// --------------- detect: top-k (full bitonic sort) + greedy NMS ------------
__global__ __launch_bounds__(1024) void detect_kernel(const float* __restrict__ mscore,
                                                      const float* __restrict__ maskS,
                                                      const float* __restrict__ mo,
                                                      const float* __restrict__ xo,
                                                      const float* __restrict__ yo,
                                                      float* __restrict__ out)
{
    int b = blockIdx.x;
    int tid = threadIdx.x;
    __shared__ unsigned long long keys[4096];
    __shared__ float sx[1024];
    __shared__ float sy[1024];
    __shared__ float sa[1024];
    __shared__ int keep[1024];

    const float* sp = mscore + b * 4096;
    const float* mp = maskS + b * 4096;
    // key = (~ord(masked_val)) << 32 | idx  -> ascending u64 sort gives
    // value-descending, index-ascending (matches jax.lax.top_k stability)
    for (int i = tid; i < 4096; i += 1024) {
        float s = sp[i] * mp[i];
        float mval = (s > 0.5f) ? s : -1.0f;
        unsigned int fb = __float_as_uint(mval);
        unsigned int od = (fb & 0x80000000u) ? ~fb : (fb | 0x80000000u);
        keys[i] = ((unsigned long long)(~od) << 32) | (unsigned int)i;
    }
    for (int k = 2; k <= 4096; k <<= 1) {
        for (int j = k >> 1; j > 0; j >>= 1) {
            __syncthreads();
            for (int t = tid; t < 4096; t += 1024) {
                int ixj = t ^ j;
                if (ixj > t) {
                    unsigned long long va = keys[t], vb = keys[ixj];
                    bool up = ((t & k) == 0);
                    if ((va > vb) == up) { keys[t] = vb; keys[ixj] = va; }
                }
            }
        }
    }
    __syncthreads();

    int idx = (int)(keys[tid] & 0xffffffffu);
    float s = sp[idx] * mp[idx];        // flat[idx] (unmasked score)
    bool valid = s > 0.5f;              // == (masked val > 0.5)
    int Nv = __syncthreads_count(valid);  // valid entries form the sorted prefix

    float xc = 0.f, yc = 0.f, ang = 0.f;
    if (tid < Nv) {
        int rr = idx >> 6, cc = idx & 63;
        const float* op = mo + (size_t)b * C_MNTc * 4096 + idx;
        float best = op[0]; int bi = 0;
        for (int ch = 1; ch < C_MNTc; ch++) {
            float v = op[ch * 4096];
            if (v > best) { best = v; bi = ch; }
        }
        const float* xp = xo + (size_t)b * C_OFFc * 4096 + idx;
        float bxv = xp[0]; int bx = 0;
        for (int ch = 1; ch < C_OFFc; ch++) {
            float v = xp[ch * 4096];
            if (v > bxv) { bxv = v; bx = ch; }
        }
        const float* yp = yo + (size_t)b * C_OFFc * 4096 + idx;
        float byv = yp[0]; int by = 0;
        for (int ch = 1; ch < C_OFFc; ch++) {
            float v = yp[ch * 4096];
            if (v > byv) { byv = v; by = ch; }
        }
        ang = ((float)bi * 2.0f - 89.0f) * PI_180;
        xc = (float)cc * 8.0f + (float)bx;
        yc = (float)rr * 8.0f + (float)by;
        sx[tid] = xc; sy[tid] = yc; sa[tid] = ang;
        keep[tid] = 1;
    } else {
        keep[tid] = 0;
    }
    __syncthreads();

    // greedy sequential NMS over the valid prefix (reference fori_loop semantics)
    for (int i = 0; i < Nv; i++) {
        if (keep[i] && tid > i && tid < Nv && keep[tid]) {
            float dx = sx[tid] - sx[i], dy = sy[tid] - sy[i];
            float d = sqrtf(dx * dx + dy * dy);
            float da = fabsf(sa[tid] - sa[i]);
            da = fminf(da, TWO_PI - da);
            if (d < 16.0f && da < ANG_T) keep[tid] = 0;
        }
        __syncthreads();
    }

    int kf = keep[tid];
    float* mout = out + O_MINUT + (size_t)b * Kc * 4 + (size_t)tid * 4;
    if (kf) {
        mout[0] = xc; mout[1] = yc; mout[2] = ang; mout[3] = s;
    } else {
        mout[0] = 0.f; mout[1] = 0.f; mout[2] = 0.f; mout[3] = 0.f;
    }
    out[O_KEEP + b * Kc + tid] = (float)kf;
}

extern "C" void kernel_launch(void* const* d_in, const int* in_sizes, int n_in,
                              void* d_out_, int out_size, void* d_ws, size_t ws_size,
                              hipStream_t stream)
{
    const float* seg    = (const float*)d_in[0];
    const float* segup  = (const float*)d_in[1];
    const float* oriup  = (const float*)d_in[2];
    const float* enh    = (const float*)d_in[3];
    const float* mscore = (const float*)d_in[4];
    const float* mori   = (const float*)d_in[5];
    const float* mxo    = (const float*)d_in[6];
    const float* myo    = (const float*)d_in[7];
    float* out = (float*)d_out_;

    float* maskS    = (float*)d_ws;            // Bn*4096
    float* partials = maskS + Bn * 4096;       // Bn*512*2
    float* mm       = partials + Bn * 512 * 2; // Bn*2

    // use final output regions as ping-pong scratch for the opening passes
    float* T1 = out + O_VIS;   // overwritten last by vis_kernel
    float* T2 = out + O_ORI;   // overwritten by final_up_kernel

    small_mask_kernel<<<Bn, 256, 0, stream>>>(seg, maskS);
    detect_kernel<<<Bn, 1024, 0, stream>>>(mscore, maskS, mori, mxo, myo, out);

    dim3 pb(64, 4);
    dim3 pg(8, 128, Bn);
    pass_v<true, true><<<pg, pb, 0, stream>>>(segup, T1);   // binarize + vertical erosion
    pass_h<true><<<pg, pb, 0, stream>>>(T1, T2);            // horizontal erosion
    pass_v<false, false><<<pg, pb, 0, stream>>>(T2, T1);    // vertical dilation
    final_up_kernel<<<dim3(Hh, Bn), 512, 0, stream>>>(T1, oriup, enh, out, partials);
    reduce_mm_kernel<<<Bn, 512, 0, stream>>>(partials, mm);
    vis_kernel<<<(Bn * Hh * Wh) / 256, 256, 0, stream>>>(enh, out + O_MASK, mm, out + O_VIS);
}

// Round 2
// 511.810 us; speedup vs baseline: 1.1312x; 1.1312x over previous
//
#include <hip/hip_runtime.h>
#include <math.h>

#define HSd 64
#define WSd 64
#define Hh 512
#define Wh 512
#define Bn 4
#define C_ORIc 90
#define C_MNTc 180
#define C_OFFc 8
#define Kc 1024

// output offsets (in floats), concatenated in return order:
// minut [B,K,4], keep [B,K], enh_vis [B,H,W], mask_up*255 [B,H,W], ori_field [B,H,W]
#define O_MINUT 0
#define O_KEEP  (Bn*Kc*4)            // 16384
#define O_VIS   (O_KEEP + Bn*Kc)     // 20480
#define O_MASK  (O_VIS + Bn*Hh*Wh)   // 1069056
#define O_ORI   (O_MASK + Bn*Hh*Wh)  // 2117632

#define PI_180 0.017453292519943295f
#define TWO_PI 6.283185307179586f
#define ANG_T  0.5235987755982988f

// ---------------- 512x512 windowed passes (k=40: lo=-19, hi=+20) -----------
template <bool ISMIN, bool BIN>
__global__ __launch_bounds__(256) void pass_v(const float* __restrict__ in,
                                              float* __restrict__ out)
{
    int c = blockIdx.x * 64 + threadIdx.x;
    int r = blockIdx.y * 4 + threadIdx.y;
    int b = blockIdx.z;
    const float* p = in + (size_t)b * Hh * Wh;
    int lo = max(r - 19, 0), hi = min(r + 20, Hh - 1);
    float acc = ISMIN ? 1e30f : -1e30f;
    for (int rr = lo; rr <= hi; rr++) {
        float v = p[rr * Wh + c];
        if (BIN) v = rintf(v);
        acc = ISMIN ? fminf(acc, v) : fmaxf(acc, v);
    }
    out[(size_t)b * Hh * Wh + (size_t)r * Wh + c] = acc;
}

template <bool ISMIN>
__global__ __launch_bounds__(256) void pass_h(const float* __restrict__ in,
                                              float* __restrict__ out)
{
    int c = blockIdx.x * 64 + threadIdx.x;
    int r = blockIdx.y * 4 + threadIdx.y;
    int b = blockIdx.z;
    const float* p = in + (size_t)b * Hh * Wh + (size_t)r * Wh;
    int lo = max(c - 19, 0), hi = min(c + 20, Wh - 1);
    float acc = ISMIN ? 1e30f : -1e30f;
    for (int cc = lo; cc <= hi; cc++)
        acc = ISMIN ? fminf(acc, p[cc]) : fmaxf(acc, p[cc]);
    out[(size_t)b * Hh * Wh + (size_t)r * Wh + c] = acc;
}

// ------- final horizontal max + mask_up*255 + ori_field + enh partials -----
__global__ __launch_bounds__(512) void final_up_kernel(const float* __restrict__ vmx,
                                                       const float* __restrict__ ori,
                                                       const float* __restrict__ enh,
                                                       float* __restrict__ out,
                                                       float* __restrict__ partials)
{
    int r = blockIdx.x, b = blockIdx.y, c = threadIdx.x;
    __shared__ float row[512];
    __shared__ float rmn[512];
    __shared__ float rmx[512];
    size_t base = (size_t)b * Hh * Wh + (size_t)r * Wh;
    row[c] = vmx[base + c];
    __syncthreads();
    int lo = max(c - 19, 0), hi = min(c + 20, Wh - 1);
    float m = -1e30f;
    for (int cc = lo; cc <= hi; cc++) m = fmaxf(m, row[cc]);
    out[O_MASK + base + c] = m * 255.0f;

    float of = 0.0f;
    if (m != 0.0f) {  // mask_up is 0/1; skip the 90-channel read when masked out
        const float* op = ori + (size_t)b * C_ORIc * Hh * Wh + (size_t)r * Wh + c;
        float best = op[0];
        int bi = 0;
        for (int ch = 1; ch < C_ORIc; ch++) {
            float v = op[(size_t)ch * Hh * Wh];
            if (v > best) { best = v; bi = ch; }
        }
        of = ((float)bi * 2.0f - 90.0f) * PI_180 * m;
    }
    out[O_ORI + base + c] = of;

    float e = enh[base + c] * m;
    rmn[c] = e; rmx[c] = e;
    __syncthreads();
    for (int s2 = 256; s2 > 0; s2 >>= 1) {
        if (c < s2) {
            rmn[c] = fminf(rmn[c], rmn[c + s2]);
            rmx[c] = fmaxf(rmx[c], rmx[c + s2]);
        }
        __syncthreads();
    }
    if (c == 0) {
        partials[(b * Hh + r) * 2 + 0] = rmn[0];
        partials[(b * Hh + r) * 2 + 1] = rmx[0];
    }
}

__global__ __launch_bounds__(512) void reduce_mm_kernel(const float* __restrict__ partials,
                                                        float* __restrict__ mm)
{
    int b = blockIdx.x, t = threadIdx.x;
    __shared__ float mn[512];
    __shared__ float mx[512];
    mn[t] = partials[(b * 512 + t) * 2 + 0];
    mx[t] = partials[(b * 512 + t) * 2 + 1];
    __syncthreads();
    for (int s = 256; s > 0; s >>= 1) {
        if (t < s) {
            mn[t] = fminf(mn[t], mn[t + s]);
            mx[t] = fmaxf(mx[t], mx[t + s]);
        }
        __syncthreads();
    }
    if (t == 0) { mm[b * 2] = mn[0]; mm[b * 2 + 1] = mx[0]; }
}

__global__ __launch_bounds__(256) void vis_kernel(const float* __restrict__ enh,
                                                  const float* __restrict__ maskout,
                                                  const float* __restrict__ mm,
                                                  float* __restrict__ vis)
{
    int idx = blockIdx.x * 256 + threadIdx.x;  // Bn*Hh*Wh total
    int b = idx >> 18;                          // 512*512 = 2^18
    float m = (maskout[idx] != 0.0f) ? 1.0f : 0.0f;
    float e = enh[idx] * m;
    float emin = mm[b * 2], emax = mm[b * 2 + 1];
    float r = (e - emin) / (emax - emin + 1e-8f);
    vis[idx] = r * 255.0f;
}

// --------------- detect (fused small-mask + fast path + sort/NMS) ----------
// LDS plan:
//   keys[4096] u64 (32 KB)  -- aliased as float scratch (needs 64*65 floats =
//                              16.6 KB) during the 5x5 opening, and as
//                              sx/sy/sa/keep (16 KB) during NMS.
//   maskT[64][65]           -- persistent small mask for batch b.
__global__ __launch_bounds__(1024) void detect_kernel(const float* __restrict__ mscore,
                                                      const float* __restrict__ seg,
                                                      const float* __restrict__ mo,
                                                      const float* __restrict__ xo,
                                                      const float* __restrict__ yo,
                                                      float* __restrict__ out)
{
    int b = blockIdx.x;
    int tid = threadIdx.x;
    __shared__ unsigned long long keys[4096];
    __shared__ float maskT[64][65];
    float* scratch = (float*)keys;   // 64*65 floats fits in 32 KB

    // ---- 5x5 opening of round(seg[b]) ----
    const float* sg = seg + b * 4096;
    // load+round -> maskT
    for (int i = tid; i < 4096; i += 1024)
        maskT[i >> 6][i & 63] = rintf(sg[i]);
    __syncthreads();
    // vertical min maskT -> scratch
    for (int i = tid; i < 4096; i += 1024) {
        int r = i >> 6, c = i & 63;
        int lo = max(r - 2, 0), hi = min(r + 2, 63);
        float m = 1e30f;
        for (int rr = lo; rr <= hi; rr++) m = fminf(m, maskT[rr][c]);
        scratch[r * 65 + c] = m;
    }
    __syncthreads();
    // horizontal min scratch -> maskT
    for (int i = tid; i < 4096; i += 1024) {
        int r = i >> 6, c = i & 63;
        int lo = max(c - 2, 0), hi = min(c + 2, 63);
        float m = 1e30f;
        for (int cc = lo; cc <= hi; cc++) m = fminf(m, scratch[r * 65 + cc]);
        maskT[r][c] = m;
    }
    __syncthreads();
    // vertical max maskT -> scratch
    for (int i = tid; i < 4096; i += 1024) {
        int r = i >> 6, c = i & 63;
        int lo = max(r - 2, 0), hi = min(r + 2, 63);
        float m = -1e30f;
        for (int rr = lo; rr <= hi; rr++) m = fmaxf(m, maskT[rr][c]);
        scratch[r * 65 + c] = m;
    }
    __syncthreads();
    // horizontal max scratch -> maskT (final mask)
    for (int i = tid; i < 4096; i += 1024) {
        int r = i >> 6, c = i & 63;
        int lo = max(c - 2, 0), hi = min(c + 2, 63);
        float m = -1e30f;
        for (int cc = lo; cc <= hi; cc++) m = fmaxf(m, scratch[r * 65 + cc]);
        maskT[r][c] = m;
    }
    __syncthreads();

    // ---- fast path: if no masked score exceeds THRESH, output is all-zero
    //      regardless of top-k ordering (valid all-false => keep all-false,
    //      minut zeroed by keep multiply). Skip sort + gathers + NMS.
    const float* sp = mscore + b * 4096;
    bool anyv = false;
    for (int i = tid; i < 4096; i += 1024) {
        float s = sp[i] * maskT[i >> 6][i & 63];
        anyv |= (s > 0.5f);
    }
    if (!__syncthreads_or(anyv)) {
        float* mout = out + O_MINUT + (size_t)b * Kc * 4 + (size_t)tid * 4;
        mout[0] = 0.f; mout[1] = 0.f; mout[2] = 0.f; mout[3] = 0.f;
        out[O_KEEP + b * Kc + tid] = 0.f;
        return;
    }

    // ---- slow path: full bitonic sort for exact jax.lax.top_k semantics ----
    // key = (~ord(masked_val)) << 32 | idx  -> ascending u64 sort gives
    // value-descending, index-ascending (matches top_k tie-break stability)
    for (int i = tid; i < 4096; i += 1024) {
        float s = sp[i] * maskT[i >> 6][i & 63];
        float mval = (s > 0.5f) ? s : -1.0f;
        unsigned int fb = __float_as_uint(mval);
        unsigned int od = (fb & 0x80000000u) ? ~fb : (fb | 0x80000000u);
        keys[i] = ((unsigned long long)(~od) << 32) | (unsigned int)i;
    }
    for (int k = 2; k <= 4096; k <<= 1) {
        for (int j = k >> 1; j > 0; j >>= 1) {
            __syncthreads();
            for (int t = tid; t < 4096; t += 1024) {
                int ixj = t ^ j;
                if (ixj > t) {
                    unsigned long long va = keys[t], vb = keys[ixj];
                    bool up = ((t & k) == 0);
                    if ((va > vb) == up) { keys[t] = vb; keys[ixj] = va; }
                }
            }
        }
    }
    __syncthreads();

    int idx = (int)(keys[tid] & 0xffffffffu);
    float s = sp[idx] * maskT[idx >> 6][idx & 63];  // flat[idx] (masked score)
    bool valid = s > 0.5f;
    int Nv = __syncthreads_count(valid);  // valid entries form the sorted prefix

    // keys no longer needed; alias NMS arrays onto that LDS
    float* sx = scratch;          // [1024]
    float* sy = scratch + 1024;   // [1024]
    float* sa = scratch + 2048;   // [1024]
    int*   keep = (int*)(scratch + 3072);  // [1024]

    float xc = 0.f, yc = 0.f, ang = 0.f;
    if (tid < Nv) {
        int rr = idx >> 6, cc = idx & 63;
        const float* op = mo + (size_t)b * C_MNTc * 4096 + idx;
        float best = op[0]; int bi = 0;
        for (int ch = 1; ch < C_MNTc; ch++) {
            float v = op[ch * 4096];
            if (v > best) { best = v; bi = ch; }
        }
        const float* xp = xo + (size_t)b * C_OFFc * 4096 + idx;
        float bxv = xp[0]; int bx = 0;
        for (int ch = 1; ch < C_OFFc; ch++) {
            float v = xp[ch * 4096];
            if (v > bxv) { bxv = v; bx = ch; }
        }
        const float* yp = yo + (size_t)b * C_OFFc * 4096 + idx;
        float byv = yp[0]; int by = 0;
        for (int ch = 1; ch < C_OFFc; ch++) {
            float v = yp[ch * 4096];
            if (v > byv) { byv = v; by = ch; }
        }
        ang = ((float)bi * 2.0f - 89.0f) * PI_180;
        xc = (float)cc * 8.0f + (float)bx;
        yc = (float)rr * 8.0f + (float)by;
        sx[tid] = xc; sy[tid] = yc; sa[tid] = ang;
        keep[tid] = 1;
    } else {
        keep[tid] = 0;
    }
    __syncthreads();

    // greedy sequential NMS over the valid prefix (reference fori_loop semantics)
    for (int i = 0; i < Nv; i++) {
        if (keep[i] && tid > i && tid < Nv && keep[tid]) {
            float dx = sx[tid] - sx[i], dy = sy[tid] - sy[i];
            float d = sqrtf(dx * dx + dy * dy);
            float da = fabsf(sa[tid] - sa[i]);
            da = fminf(da, TWO_PI - da);
            if (d < 16.0f && da < ANG_T) keep[tid] = 0;
        }
        __syncthreads();
    }

    int kf = keep[tid];
    float* mout = out + O_MINUT + (size_t)b * Kc * 4 + (size_t)tid * 4;
    if (kf) {
        mout[0] = xc; mout[1] = yc; mout[2] = ang; mout[3] = s;
    } else {
        mout[0] = 0.f; mout[1] = 0.f; mout[2] = 0.f; mout[3] = 0.f;
    }
    out[O_KEEP + b * Kc + tid] = (float)kf;
}

extern "C" void kernel_launch(void* const* d_in, const int* in_sizes, int n_in,
                              void* d_out_, int out_size, void* d_ws, size_t ws_size,
                              hipStream_t stream)
{
    const float* seg    = (const float*)d_in[0];
    const float* segup  = (const float*)d_in[1];
    const float* oriup  = (const float*)d_in[2];
    const float* enh    = (const float*)d_in[3];
    const float* mscore = (const float*)d_in[4];
    const float* mori   = (const float*)d_in[5];
    const float* mxo    = (const float*)d_in[6];
    const float* myo    = (const float*)d_in[7];
    float* out = (float*)d_out_;

    float* partials = (float*)d_ws;            // Bn*512*2
    float* mm       = partials + Bn * 512 * 2; // Bn*2

    // use final output regions as ping-pong scratch for the opening passes
    float* T1 = out + O_VIS;   // overwritten last by vis_kernel
    float* T2 = out + O_ORI;   // overwritten by final_up_kernel

    detect_kernel<<<Bn, 1024, 0, stream>>>(mscore, seg, mori, mxo, myo, out);

    dim3 pb(64, 4);
    dim3 pg(8, 128, Bn);
    pass_v<true, true><<<pg, pb, 0, stream>>>(segup, T1);   // binarize + vertical erosion
    pass_h<true><<<pg, pb, 0, stream>>>(T1, T2);            // horizontal erosion
    pass_v<false, false><<<pg, pb, 0, stream>>>(T2, T1);    // vertical dilation
    final_up_kernel<<<dim3(Hh, Bn), 512, 0, stream>>>(T1, oriup, enh, out, partials);
    reduce_mm_kernel<<<Bn, 512, 0, stream>>>(partials, mm);
    vis_kernel<<<(Bn * Hh * Wh) / 256, 256, 0, stream>>>(enh, out + O_MASK, mm, out + O_VIS);
}